// Round 1
// baseline (134.461 us; speedup 1.0000x reference)
//
#include <hip/hip_runtime.h>

// Problem: B=8, C=64, W=256, H=256, fp32.
// out[b,c,w,h] = sig(Wc@mean_wh(x)+bc)[b,c] * sig(Ww@mean_ch(x)+bw)[b,w] * sig(Wh@mean_cw(x)+bh)[b,h]
// Memory-bound: read 134MB + write 134MB.

#define NB 8
#define NC 64
#define NW 256
#define NH 256

// ws float layout:
// [0,512)      sum_c   (B*C)
// [512,2560)   sum_w   (B*W)
// [2560,4608)  sum_h   (B*H)
// [4608,5120)  gate_c
// [5120,7168)  gate_w
// [7168,9216)  gate_h

__global__ __launch_bounds__(256) void pool_kernel(const float* __restrict__ x,
                                                   float* __restrict__ ws) {
    float* sum_c = ws;
    float* sum_w = ws + 512;
    float* sum_h = ws + 2560;

    int bc = blockIdx.x;           // b*64 + c
    int b  = bc >> 6;
    int tid  = threadIdx.x;        // 0..255
    int wv   = tid >> 6;           // wave 0..3
    int lane = tid & 63;

    const float4* xr = (const float4*)x + (size_t)bc * (NW * (NH / 4));

    float4 col = make_float4(0.f, 0.f, 0.f, 0.f);
    // each wave owns rows wv, wv+4, ... ; 64 lanes x float4 = full row of 256
    for (int w = wv; w < NW; w += 4) {
        float4 v = xr[w * (NH / 4) + lane];
        col.x += v.x; col.y += v.y; col.z += v.z; col.w += v.w;
        float rs = v.x + v.y + v.z + v.w;
        #pragma unroll
        for (int off = 32; off; off >>= 1) rs += __shfl_xor(rs, off);
        if (lane == 0) atomicAdd(&sum_w[b * NW + w], rs);
    }

    __shared__ float cols[4][NH];
    cols[wv][lane * 4 + 0] = col.x;
    cols[wv][lane * 4 + 1] = col.y;
    cols[wv][lane * 4 + 2] = col.z;
    cols[wv][lane * 4 + 3] = col.w;
    __syncthreads();

    float cv = cols[0][tid] + cols[1][tid] + cols[2][tid] + cols[3][tid];
    atomicAdd(&sum_h[b * NH + tid], cv);

    // block total -> sum_c (this block covers the whole (b,c) slice)
    float t = cv;
    #pragma unroll
    for (int off = 32; off; off >>= 1) t += __shfl_xor(t, off);
    __shared__ float wpart[4];
    if (lane == 0) wpart[wv] = t;
    __syncthreads();
    if (tid == 0) sum_c[bc] = wpart[0] + wpart[1] + wpart[2] + wpart[3];
}

__global__ __launch_bounds__(256) void gates_kernel(const float* __restrict__ Wc, const float* __restrict__ bc_,
                                                    const float* __restrict__ Ww, const float* __restrict__ bw_,
                                                    const float* __restrict__ Wh, const float* __restrict__ bh_,
                                                    float* __restrict__ ws) {
    const float* sum_c = ws;
    const float* sum_w = ws + 512;
    const float* sum_h = ws + 2560;
    float* gate_c = ws + 4608;
    float* gate_w = ws + 5120;
    float* gate_h = ws + 7168;

    int j = blockIdx.x * 4 + (threadIdx.x >> 6);  // global wave id, 0..4607
    int lane = threadIdx.x & 63;

    float acc = 0.f, bias;
    float* dst;
    if (j < 512) {                                 // c-gate: dot length 64
        int b = j >> 6, o = j & 63;
        acc = Wc[o * 64 + lane] * sum_c[b * 64 + lane] * (1.f / 65536.f);
        bias = bc_[o];
        dst = &gate_c[j];
    } else if (j < 2560) {                         // w-gate: dot length 256
        int j2 = j - 512;
        int b = j2 >> 8, o = j2 & 255;
        const float* wr = Ww + o * 256;
        const float* sr = sum_w + b * 256;
        #pragma unroll
        for (int m = 0; m < 4; ++m) acc += wr[lane + 64 * m] * sr[lane + 64 * m];
        acc *= (1.f / 16384.f);
        bias = bw_[o];
        dst = &gate_w[j2];
    } else {                                       // h-gate: dot length 256
        int j2 = j - 2560;
        int b = j2 >> 8, o = j2 & 255;
        const float* wr = Wh + o * 256;
        const float* sr = sum_h + b * 256;
        #pragma unroll
        for (int m = 0; m < 4; ++m) acc += wr[lane + 64 * m] * sr[lane + 64 * m];
        acc *= (1.f / 16384.f);
        bias = bh_[o];
        dst = &gate_h[j2];
    }
    #pragma unroll
    for (int off = 32; off; off >>= 1) acc += __shfl_xor(acc, off);
    if (lane == 0) *dst = 1.f / (1.f + expf(-(acc + bias)));
}

__global__ __launch_bounds__(256) void out_kernel(const float* __restrict__ ws,
                                                  float4* __restrict__ out) {
    const float* gate_c = ws + 4608;
    const float* gate_w = ws + 5120;
    const float4* gate_h4 = (const float4*)(ws + 7168);

    const size_t N4 = (size_t)NB * NC * NW * (NH / 4);  // 8388608
    size_t stride = (size_t)gridDim.x * blockDim.x;
    for (size_t i = (size_t)blockIdx.x * blockDim.x + threadIdx.x; i < N4; i += stride) {
        int h4 = (int)(i & 63);          // H/4 = 64
        size_t row = i >> 6;
        int w = (int)(row & 255);        // W = 256
        size_t bcr = row >> 8;
        int c = (int)(bcr & 63);         // C = 64
        int b = (int)(bcr >> 6);
        float g = gate_c[b * 64 + c] * gate_w[b * 256 + w];
        float4 gh = gate_h4[b * 64 + h4];
        out[i] = make_float4(g * gh.x, g * gh.y, g * gh.z, g * gh.w);
    }
}

extern "C" void kernel_launch(void* const* d_in, const int* in_sizes, int n_in,
                              void* d_out, int out_size, void* d_ws, size_t ws_size,
                              hipStream_t stream) {
    const float* x   = (const float*)d_in[0];
    const float* Wc  = (const float*)d_in[1];
    const float* bc_ = (const float*)d_in[2];
    const float* Ww  = (const float*)d_in[3];
    const float* bw_ = (const float*)d_in[4];
    const float* Wh  = (const float*)d_in[5];
    const float* bh_ = (const float*)d_in[6];
    float* ws = (float*)d_ws;

    // zero the atomic accumulators (sum_c, sum_w, sum_h) every call
    hipMemsetAsync(ws, 0, 4608 * sizeof(float), stream);

    pool_kernel<<<NB * NC, 256, 0, stream>>>(x, ws);
    gates_kernel<<<4608 / 4, 256, 0, stream>>>(Wc, bc_, Ww, bw_, Wh, bh_, ws);
    out_kernel<<<2048, 256, 0, stream>>>(ws, (float4*)d_out);
}

// Round 2
// 58.573 us; speedup vs baseline: 2.2956x; 2.2956x over previous
//
#include <hip/hip_runtime.h>

// Problem: B=8, C=64, W=256, H=256, fp32.
// out[b,c,w,h] = sig(Wc@mean_wh(x)+bc)[b,c] * sig(Ww@mean_ch(x)+bw)[b,w] * sig(Wh@mean_cw(x)+bh)[b,h]
// Memory-bound: read 134MB + write 134MB. Round 1 lesson: keep atomics and
// cross-lane reduces OUT of the load loop (vmcnt is in-order; a contended
// atomic in the loop serializes every subsequent load's waitcnt).

#define NB 8
#define NC 64
#define NW 256
#define NH 256

// ws float layout:
// [0,512)      sum_c   (B*C)
// [512,2560)   sum_w   (B*W)
// [2560,4608)  sum_h   (B*H)
// [4608,5120)  gate_c
// [5120,7168)  gate_w
// [7168,9216)  gate_h

__global__ __launch_bounds__(256) void pool_kernel(const float* __restrict__ x,
                                                   float* __restrict__ ws) {
    float* sum_c = ws;
    float* sum_w = ws + 512;
    float* sum_h = ws + 2560;

    int blk  = blockIdx.x;         // 0..1023
    int bc   = blk >> 1;           // b*64 + c
    int half = blk & 1;            // which 128-row half of the slice
    int b    = bc >> 6;
    int tid  = threadIdx.x;        // 0..255
    int wv   = tid >> 6;           // wave 0..3
    int lane = tid & 63;

    const float4* xr = (const float4*)x + (size_t)bc * (NW * (NH / 4));
    int wbase = half * 128;

    float4 col = make_float4(0.f, 0.f, 0.f, 0.f);
    __shared__ float rowsum[4][32];   // [wave][k] : row w = wbase + wv + 4k
    __shared__ float cols[4][NH];
    __shared__ float wpart[4];

    // wave wv owns rows w = wbase + wv + 4k, k=0..31, in batches of 8 so that
    // 8 global_load_dwordx4 are in flight before any dependent VALU.
    for (int kb = 0; kb < 32; kb += 8) {
        float4 v[8];
        #pragma unroll
        for (int i = 0; i < 8; ++i)
            v[i] = xr[(wbase + wv + 4 * (kb + i)) * (NH / 4) + lane];
        float rs[8];
        #pragma unroll
        for (int i = 0; i < 8; ++i) {
            col.x += v[i].x; col.y += v[i].y; col.z += v[i].z; col.w += v[i].w;
            rs[i] = (v[i].x + v[i].y) + (v[i].z + v[i].w);
        }
        // 8 independent butterfly chains -> ILP hides shuffle latency
        #pragma unroll
        for (int off = 32; off; off >>= 1) {
            #pragma unroll
            for (int i = 0; i < 8; ++i) rs[i] += __shfl_xor(rs[i], off);
        }
        #pragma unroll
        for (int i = 0; i < 8; ++i)
            if (lane == i) rowsum[wv][kb + i] = rs[i];   // every lane has the sum
    }

    cols[wv][lane * 4 + 0] = col.x;
    cols[wv][lane * 4 + 1] = col.y;
    cols[wv][lane * 4 + 2] = col.z;
    cols[wv][lane * 4 + 3] = col.w;
    __syncthreads();

    // h-partials: thread t owns column h=t
    float cv = cols[0][tid] + cols[1][tid] + cols[2][tid] + cols[3][tid];
    atomicAdd(&sum_h[b * NH + tid], cv);

    // row sums: threads 0..127 flush the 128 rows, coalesced addresses
    if (tid < 128)
        atomicAdd(&sum_w[b * NW + wbase + tid], rowsum[tid & 3][tid >> 2]);

    // block total -> sum_c (2 blocks per slice -> atomic)
    float t = cv;
    #pragma unroll
    for (int off = 32; off; off >>= 1) t += __shfl_xor(t, off);
    if (lane == 0) wpart[wv] = t;
    __syncthreads();
    if (tid == 0) atomicAdd(&sum_c[bc], wpart[0] + wpart[1] + wpart[2] + wpart[3]);
}

__global__ __launch_bounds__(256) void gates_kernel(const float* __restrict__ Wc, const float* __restrict__ bc_,
                                                    const float* __restrict__ Ww, const float* __restrict__ bw_,
                                                    const float* __restrict__ Wh, const float* __restrict__ bh_,
                                                    float* __restrict__ ws) {
    const float* sum_c = ws;
    const float* sum_w = ws + 512;
    const float* sum_h = ws + 2560;
    float* gate_c = ws + 4608;
    float* gate_w = ws + 5120;
    float* gate_h = ws + 7168;

    int j = blockIdx.x * 4 + (threadIdx.x >> 6);  // global wave id, 0..4607
    int lane = threadIdx.x & 63;

    float acc = 0.f, bias;
    float* dst;
    if (j < 512) {                                 // c-gate: dot length 64
        int b = j >> 6, o = j & 63;
        acc = Wc[o * 64 + lane] * sum_c[b * 64 + lane] * (1.f / 65536.f);
        bias = bc_[o];
        dst = &gate_c[j];
    } else if (j < 2560) {                         // w-gate: dot length 256
        int j2 = j - 512;
        int b = j2 >> 8, o = j2 & 255;
        const float* wr = Ww + o * 256;
        const float* sr = sum_w + b * 256;
        #pragma unroll
        for (int m = 0; m < 4; ++m) acc += wr[lane + 64 * m] * sr[lane + 64 * m];
        acc *= (1.f / 16384.f);
        bias = bw_[o];
        dst = &gate_w[j2];
    } else {                                       // h-gate: dot length 256
        int j2 = j - 2560;
        int b = j2 >> 8, o = j2 & 255;
        const float* wr = Wh + o * 256;
        const float* sr = sum_h + b * 256;
        #pragma unroll
        for (int m = 0; m < 4; ++m) acc += wr[lane + 64 * m] * sr[lane + 64 * m];
        acc *= (1.f / 16384.f);
        bias = bh_[o];
        dst = &gate_h[j2];
    }
    #pragma unroll
    for (int off = 32; off; off >>= 1) acc += __shfl_xor(acc, off);
    if (lane == 0) *dst = 1.f / (1.f + expf(-(acc + bias)));
}

__global__ __launch_bounds__(256) void out_kernel(const float* __restrict__ ws,
                                                  float4* __restrict__ out) {
    const float* gate_c = ws + 4608;
    const float* gate_w = ws + 5120;
    const float4* gate_h4 = (const float4*)(ws + 7168);

    const size_t N4 = (size_t)NB * NC * NW * (NH / 4);  // 8388608
    size_t stride = (size_t)gridDim.x * blockDim.x;
    for (size_t i = (size_t)blockIdx.x * blockDim.x + threadIdx.x; i < N4; i += stride) {
        int h4 = (int)(i & 63);          // H/4 = 64
        size_t row = i >> 6;
        int w = (int)(row & 255);        // W = 256
        size_t bcr = row >> 8;
        int c = (int)(bcr & 63);         // C = 64
        int b = (int)(bcr >> 6);
        float g = gate_c[b * 64 + c] * gate_w[b * 256 + w];
        float4 gh = gate_h4[b * 64 + h4];
        out[i] = make_float4(g * gh.x, g * gh.y, g * gh.z, g * gh.w);
    }
}

extern "C" void kernel_launch(void* const* d_in, const int* in_sizes, int n_in,
                              void* d_out, int out_size, void* d_ws, size_t ws_size,
                              hipStream_t stream) {
    const float* x   = (const float*)d_in[0];
    const float* Wc  = (const float*)d_in[1];
    const float* bc_ = (const float*)d_in[2];
    const float* Ww  = (const float*)d_in[3];
    const float* bw_ = (const float*)d_in[4];
    const float* Wh  = (const float*)d_in[5];
    const float* bh_ = (const float*)d_in[6];
    float* ws = (float*)d_ws;

    // zero the atomic accumulators (sum_c, sum_w, sum_h) every call
    hipMemsetAsync(ws, 0, 4608 * sizeof(float), stream);

    pool_kernel<<<1024, 256, 0, stream>>>(x, ws);
    gates_kernel<<<4608 / 4, 256, 0, stream>>>(Wc, bc_, Ww, bw_, Wh, bh_, ws);
    out_kernel<<<2048, 256, 0, stream>>>(ws, (float4*)d_out);
}

// Round 3
// 58.539 us; speedup vs baseline: 2.2969x; 1.0006x over previous
//
#include <hip/hip_runtime.h>

// Problem: B=8, C=64, W=256, H=256, fp32.
// out[b,c,w,h] = sig(Wc@mean_wh(x)+bc)[b,c] * sig(Ww@mean_ch(x)+bw)[b,w] * sig(Wh@mean_cw(x)+bh)[b,h]
// Memory-bound: read 134MB + write 134MB.
// R1 lesson: no atomics/reduces inside the load loop (in-order vmcnt).
// R2 lesson: tiny hipMemsetAsync is a whole extra dispatch; out-writes evict x
//            from L3 (134+134 > 256MB) -> use nt stores for out, and use d_out
//            itself as scratch for partials so no atomics/memset are needed.

#define NB 8
#define NC 64
#define NW 256
#define NH 256

typedef float f4v __attribute__((ext_vector_type(4)));

// ws float layout (36KB, proven safe):
// [0,512)      sum_c   [512,2560) sum_w   [2560,4608) sum_h
// [4608,5120)  gate_c  [5120,7168) gate_w [7168,9216) gate_h
//
// d_out-head scratch float layout (overwritten by out_kernel at the end):
// part_c [0,1024)                 one per block
// part_w [1024,132096)            [bc=512][w=256], each block writes its 128-row half
// part_h [132096,394240)          [blk=1024][h=256]

__global__ __launch_bounds__(256) void pool_kernel(const float* __restrict__ x,
                                                   float* __restrict__ ps) {
    float* part_c = ps;
    float* part_w = ps + 1024;
    float* part_h = ps + 132096;

    int blk  = blockIdx.x;         // 0..1023
    int bc   = blk >> 1;           // b*64 + c
    int half = blk & 1;
    int tid  = threadIdx.x;
    int wv   = tid >> 6;
    int lane = tid & 63;

    const float4* xr = (const float4*)x + (size_t)bc * (NW * (NH / 4));
    int wbase = half * 128;

    float4 col = make_float4(0.f, 0.f, 0.f, 0.f);
    __shared__ float rowsum[4][32];   // [wave][k] : row w = wbase + wv + 4k
    __shared__ float cols[4][NH];
    __shared__ float wpart[4];

    // wave wv owns rows w = wbase + wv + 4k, k=0..31; 16 loads in flight.
    for (int kb = 0; kb < 32; kb += 16) {
        float4 v[16];
        #pragma unroll
        for (int i = 0; i < 16; ++i)
            v[i] = xr[(wbase + wv + 4 * (kb + i)) * (NH / 4) + lane];
        float rs[16];
        #pragma unroll
        for (int i = 0; i < 16; ++i) {
            col.x += v[i].x; col.y += v[i].y; col.z += v[i].z; col.w += v[i].w;
            rs[i] = (v[i].x + v[i].y) + (v[i].z + v[i].w);
        }
        #pragma unroll
        for (int off = 32; off; off >>= 1) {
            #pragma unroll
            for (int i = 0; i < 16; ++i) rs[i] += __shfl_xor(rs[i], off);
        }
        #pragma unroll
        for (int i = 0; i < 16; ++i)
            if (lane == i) rowsum[wv][kb + i] = rs[i];
    }

    cols[wv][lane * 4 + 0] = col.x;
    cols[wv][lane * 4 + 1] = col.y;
    cols[wv][lane * 4 + 2] = col.z;
    cols[wv][lane * 4 + 3] = col.w;
    __syncthreads();

    // h-partials: thread t owns column h=t
    float cv = cols[0][tid] + cols[1][tid] + cols[2][tid] + cols[3][tid];
    part_h[(size_t)blk * 256 + tid] = cv;

    // row sums, coalesced
    if (tid < 128)
        part_w[(size_t)bc * 256 + wbase + tid] = rowsum[tid & 3][tid >> 2];

    // block total
    float t = cv;
    #pragma unroll
    for (int off = 32; off; off >>= 1) t += __shfl_xor(t, off);
    if (lane == 0) wpart[wv] = t;
    __syncthreads();
    if (tid == 0) part_c[blk] = wpart[0] + wpart[1] + wpart[2] + wpart[3];
}

__global__ __launch_bounds__(256) void reduce_kernel(const float* __restrict__ ps,
                                                     float* __restrict__ ws) {
    const float* part_c = ps;
    const float* part_w = ps + 1024;
    const float* part_h = ps + 132096;
    int t = threadIdx.x, blk = blockIdx.x;

    if (blk < 8) {                       // sum_h for b=blk: 128 partials
        const float* p = part_h + (size_t)blk * 128 * 256 + t;
        float s = 0.f;
        #pragma unroll 8
        for (int j = 0; j < 128; ++j) s += p[j * 256];
        ws[2560 + blk * 256 + t] = s;
    } else if (blk < 16) {               // sum_w for b=blk-8: 64 partials
        int b = blk - 8;
        const float* p = part_w + (size_t)b * 64 * 256 + t;
        float s = 0.f;
        #pragma unroll 8
        for (int c = 0; c < 64; ++c) s += p[c * 256];
        ws[512 + b * 256 + t] = s;
    } else {                             // sum_c: 512 outputs, 2 partials each
        ws[t]       = part_c[2 * t]         + part_c[2 * t + 1];
        ws[256 + t] = part_c[2 * (256 + t)] + part_c[2 * (256 + t) + 1];
    }
}

__global__ __launch_bounds__(256) void gates_kernel(const float* __restrict__ Wc, const float* __restrict__ bc_,
                                                    const float* __restrict__ Ww, const float* __restrict__ bw_,
                                                    const float* __restrict__ Wh, const float* __restrict__ bh_,
                                                    float* __restrict__ ws) {
    const float* sum_c = ws;
    const float* sum_w = ws + 512;
    const float* sum_h = ws + 2560;
    float* gate_c = ws + 4608;
    float* gate_w = ws + 5120;
    float* gate_h = ws + 7168;

    int j = blockIdx.x * 4 + (threadIdx.x >> 6);  // global wave id, 0..4607
    int lane = threadIdx.x & 63;

    float acc = 0.f, bias;
    float* dst;
    if (j < 512) {                                 // c-gate: dot length 64
        int b = j >> 6, o = j & 63;
        acc = Wc[o * 64 + lane] * sum_c[b * 64 + lane] * (1.f / 65536.f);
        bias = bc_[o];
        dst = &gate_c[j];
    } else if (j < 2560) {                         // w-gate: dot length 256
        int j2 = j - 512;
        int b = j2 >> 8, o = j2 & 255;
        const float* wr = Ww + o * 256;
        const float* sr = sum_w + b * 256;
        #pragma unroll
        for (int m = 0; m < 4; ++m) acc += wr[lane + 64 * m] * sr[lane + 64 * m];
        acc *= (1.f / 16384.f);
        bias = bw_[o];
        dst = &gate_w[j2];
    } else {                                       // h-gate: dot length 256
        int j2 = j - 2560;
        int b = j2 >> 8, o = j2 & 255;
        const float* wr = Wh + o * 256;
        const float* sr = sum_h + b * 256;
        #pragma unroll
        for (int m = 0; m < 4; ++m) acc += wr[lane + 64 * m] * sr[lane + 64 * m];
        acc *= (1.f / 16384.f);
        bias = bh_[o];
        dst = &gate_h[j2];
    }
    #pragma unroll
    for (int off = 32; off; off >>= 1) acc += __shfl_xor(acc, off);
    if (lane == 0) *dst = 1.f / (1.f + expf(-(acc + bias)));
}

__global__ __launch_bounds__(256) void out_kernel(const float* __restrict__ ws,
                                                  float* __restrict__ out) {
    const float* gate_c = ws + 4608;
    const float* gate_w = ws + 5120;
    const float4* gate_h4 = (const float4*)(ws + 7168);

    const size_t N4 = (size_t)NB * NC * NW * (NH / 4);  // 8388608
    size_t stride = (size_t)gridDim.x * blockDim.x;
    for (size_t i = (size_t)blockIdx.x * blockDim.x + threadIdx.x; i < N4; i += stride) {
        int h4 = (int)(i & 63);          // H/4 = 64
        size_t row = i >> 6;
        int w = (int)(row & 255);        // W = 256
        size_t bcr = row >> 8;
        int c = (int)(bcr & 63);         // C = 64
        int b = (int)(bcr >> 6);
        float g = gate_c[b * 64 + c] * gate_w[b * 256 + w];
        float4 gh = gate_h4[b * 64 + h4];
        f4v val = {g * gh.x, g * gh.y, g * gh.z, g * gh.w};
        // non-temporal: don't let the 134MB output evict x from L3
        __builtin_nontemporal_store(val, (f4v*)(out + 4 * i));
    }
}

extern "C" void kernel_launch(void* const* d_in, const int* in_sizes, int n_in,
                              void* d_out, int out_size, void* d_ws, size_t ws_size,
                              hipStream_t stream) {
    const float* x   = (const float*)d_in[0];
    const float* Wc  = (const float*)d_in[1];
    const float* bc_ = (const float*)d_in[2];
    const float* Ww  = (const float*)d_in[3];
    const float* bw_ = (const float*)d_in[4];
    const float* Wh  = (const float*)d_in[5];
    const float* bh_ = (const float*)d_in[6];
    float* ws = (float*)d_ws;
    float* ps = (float*)d_out;   // head of d_out = partials scratch (overwritten later)

    pool_kernel<<<1024, 256, 0, stream>>>(x, ps);
    reduce_kernel<<<17, 256, 0, stream>>>(ps, ws);
    gates_kernel<<<4608 / 4, 256, 0, stream>>>(Wc, bc_, Ww, bw_, Wh, bh_, ws);
    out_kernel<<<2048, 256, 0, stream>>>(ws, (float*)d_out);
}